// Round 4
// baseline (297.244 us; speedup 1.0000x reference)
//
#include <hip/hip_runtime.h>
#include <math.h>

#define QDIM 64
#define HDIM 64
#define M_NB 64
#define BLOCK 256

typedef float f4 __attribute__((ext_vector_type(4)));

// ---------------- K1: per-atom MLP chain rule + minimum-image r2 ----------------
// One wave per atom, 4 atoms per block. Writes de_dq[N,64] and r2[N,64] to ws.
__global__ __launch_bounds__(BLOCK) void tnep_setup(
    const float* __restrict__ desc,   // [N,Q]
    const float* __restrict__ pos,    // [N,3]
    const float* __restrict__ box,    // [3,3]
    const float* __restrict__ W0,     // [T,Q,H]
    const float* __restrict__ b0,     // [T,H]
    const float* __restrict__ W1,     // [T,H]
    const int*   __restrict__ Z,      // [N]
    const int*   __restrict__ gidx,   // [N,M]
    float* __restrict__ de_out,       // [N,64]
    float* __restrict__ r2_out)       // [N,64]
{
    __shared__ __align__(16) float desc_s[4][QDIM];
    __shared__ __align__(16) float g_s[4][HDIM];

    const int tid  = threadIdx.x;
    const int w    = tid >> 6;
    const int lane = tid & 63;
    const int n    = blockIdx.x * 4 + w;

    desc_s[w][lane] = desc[n * QDIM + lane];

    // ---- r2 for neighbor m = lane (minimum image; j==n gives exactly 0) ----
    {
        int j = gidx[n * M_NB + lane];
        float B[9];
        #pragma unroll
        for (int k = 0; k < 9; ++k) B[k] = box[k];
        float det = B[0]*(B[4]*B[8]-B[5]*B[7])
                  - B[1]*(B[3]*B[8]-B[5]*B[6])
                  + B[2]*(B[3]*B[7]-B[4]*B[6]);
        float inv = 1.0f / det;
        float IB[9];
        IB[0] = (B[4]*B[8]-B[5]*B[7])*inv;
        IB[1] = (B[2]*B[7]-B[1]*B[8])*inv;
        IB[2] = (B[1]*B[5]-B[2]*B[4])*inv;
        IB[3] = (B[5]*B[6]-B[3]*B[8])*inv;
        IB[4] = (B[0]*B[8]-B[2]*B[6])*inv;
        IB[5] = (B[2]*B[3]-B[0]*B[5])*inv;
        IB[6] = (B[3]*B[7]-B[4]*B[6])*inv;
        IB[7] = (B[1]*B[6]-B[0]*B[7])*inv;
        IB[8] = (B[0]*B[4]-B[1]*B[3])*inv;
        float dx = pos[j*3+0] - pos[n*3+0];
        float dy = pos[j*3+1] - pos[n*3+1];
        float dz = pos[j*3+2] - pos[n*3+2];
        float sx = dx*IB[0] + dy*IB[3] + dz*IB[6];
        float sy = dx*IB[1] + dy*IB[4] + dz*IB[7];
        float sz = dx*IB[2] + dy*IB[5] + dz*IB[8];
        sx -= rintf(sx); sy -= rintf(sy); sz -= rintf(sz);
        float ex = sx*B[0] + sy*B[3] + sz*B[6];
        float ey = sx*B[1] + sy*B[4] + sz*B[7];
        float ez = sx*B[2] + sy*B[5] + sz*B[8];
        r2_out[n * M_NB + lane] = ex*ex + ey*ey + ez*ez;
    }
    __syncthreads();

    // ---- MLP forward: lane = h ----
    const int z = Z[n];
    const float* W0t = W0 + (size_t)z * QDIM * HDIM;
    float t = b0[z * HDIM + lane];
    #pragma unroll 8
    for (int q = 0; q < QDIM; ++q)
        t += desc_s[w][q] * W0t[q * HDIM + lane];
    float ha = tanhf(t);
    g_s[w][lane] = (1.0f - ha * ha) * W1[z * HDIM + lane];
    __syncthreads();

    // ---- chain rule: de_dq[q] = g . W0[q,:]  (lane = q) ----
    {
        float de = 0.0f;
        const float* W0row = W0t + lane * HDIM;
        #pragma unroll
        for (int h4 = 0; h4 < HDIM / 4; ++h4) {
            float4 wv = *(const float4*)(W0row + h4 * 4);
            float4 gv = *(const float4*)(&g_s[w][h4 * 4]);
            de += wv.x*gv.x + wv.y*gv.y + wv.z*gv.z + wv.w*gv.w;
        }
        de_out[n * QDIM + lane] = de;
    }
}

// ---------------- K2: fill-shaped streamer ----------------
// Whole-GPU contiguous grid-stride walk over gradients (float4 granularity),
// exactly like the 6.8 TB/s fill kernel's pattern. Total float4s = N*M*3*Q/4
// = 12,582,912 = 262144 threads x 48 iters, stride 262144.
//   f = tid + i*262144 (float4 index)
//   q4 = f & 15            -> stride%16==0  => CONSTANT per thread
//   rc = f >> 4  (c-row);  c = rc%3 cycles +1/iter (16384%3==1)
//   rm = rc/3 = n*64+m;    rm += 5461 + (c==2) per iter (incremental, no div)
// de/r2 lookups (2 MB) are L2-resident; gradient loads nontemporal.
__global__ __launch_bounds__(BLOCK) void tnep_stream(
    const float* __restrict__ grad,   // [N,M,3,Q]
    const float* __restrict__ de,     // [N,64]
    const float* __restrict__ r2w,    // [N,64]
    float* __restrict__ part,         // [3, nblk]
    int nblk)
{
    __shared__ float red_s[3][4];

    const int t    = threadIdx.x;
    const int blk  = blockIdx.x;
    const int w    = t >> 6;
    const int lane = t & 63;

    const unsigned tidg = blk * BLOCK + t;        // 0..262143
    const int q4  = tidg & 15;                    // constant float4-within-row
    const unsigned rc0 = tidg >> 4;
    const unsigned rm0 = rc0 / 3u;                // compiler emits magic mul
    const int c0  = (int)(rc0 - 3u * rm0);

    // per-phase selectors (c cycles c0, c0+1, c0+2 mod 3 over iterations)
    float s0[3], s1[3], s2[3];
    unsigned drm[3];
    #pragma unroll
    for (int rr = 0; rr < 3; ++rr) {
        int c = c0 + rr; if (c >= 3) c -= 3;
        s0[rr] = (c == 0) ? 1.f : 0.f;
        s1[rr] = (c == 1) ? 1.f : 0.f;
        s2[rr] = (c == 2) ? 1.f : 0.f;
        drm[rr] = 5461u + ((c == 2) ? 1u : 0u);
    }

    const f4* gp  = (const f4*)grad + tidg;
    const f4* de4 = (const f4*)de;

    float acc0 = 0.f, acc1 = 0.f, acc2 = 0.f;
    unsigned rm = rm0;
    #pragma unroll
    for (int o = 0; o < 16; ++o) {
        #pragma unroll
        for (int rr = 0; rr < 3; ++rr) {
            const int i = o * 3 + rr;
            f4 gv = __builtin_nontemporal_load(gp + (size_t)i * 262144u);
            unsigned n = rm >> 6;
            unsigned m = rm & 63u;
            f4 df = de4[n * 16u + q4];            // L2-resident, lanes coalesce
            float r2v = r2w[rm];                  // r2w[n*64+m] == r2w[rm]
            float dot = gv.x*df.x + gv.y*df.y + gv.z*df.z + gv.w*df.w;
            float contrib = r2v * dot;
            acc0 = fmaf(s0[rr], contrib, acc0);
            acc1 = fmaf(s1[rr], contrib, acc1);
            acc2 = fmaf(s2[rr], contrib, acc2);
            rm += drm[rr];
        }
    }

    #pragma unroll
    for (int off = 32; off > 0; off >>= 1) {
        acc0 += __shfl_down(acc0, off, 64);
        acc1 += __shfl_down(acc1, off, 64);
        acc2 += __shfl_down(acc2, off, 64);
    }
    if (lane == 0) { red_s[0][w] = acc0; red_s[1][w] = acc1; red_s[2][w] = acc2; }
    __syncthreads();
    if (t < 3) {
        part[t * nblk + blk] = red_s[t][0] + red_s[t][1] + red_s[t][2] + red_s[t][3];
    }
}

// ---------------- K3: final reduce ----------------
__global__ __launch_bounds__(256) void tnep_reduce(
    const float* __restrict__ part, float* __restrict__ out, int nblk)
{
    const int t = threadIdx.x, w = t >> 6, lane = t & 63;
    if (w < 3) {
        float s = 0.f;
        for (int b = lane; b < nblk; b += 64) s += part[w * nblk + b];
        #pragma unroll
        for (int off = 32; off > 0; off >>= 1) s += __shfl_down(s, off, 64);
        if (lane == 0) out[w] = -s;
    }
}

extern "C" void kernel_launch(void* const* d_in, const int* in_sizes, int n_in,
                              void* d_out, int out_size, void* d_ws, size_t ws_size,
                              hipStream_t stream) {
    const float* desc = (const float*)d_in[0];
    const float* grad = (const float*)d_in[1];
    const float* pos  = (const float*)d_in[2];
    const float* box  = (const float*)d_in[3];
    const float* W0   = (const float*)d_in[4];
    const float* b0   = (const float*)d_in[5];
    const float* W1   = (const float*)d_in[6];
    const int*   Z    = (const int*)d_in[7];
    const int*   gidx = (const int*)d_in[8];

    const int N    = in_sizes[0] / QDIM;   // 4096
    const int nblk = N / 4;                // 1024

    float* part  = (float*)d_ws;                    // [3, nblk]
    float* de_ws = (float*)d_ws + 8192;             // [N, 64]
    float* r2_ws = de_ws + (size_t)N * 64;          // [N, 64]

    tnep_setup<<<nblk, BLOCK, 0, stream>>>(desc, pos, box, W0, b0, W1, Z, gidx,
                                           de_ws, r2_ws);
    tnep_stream<<<nblk, BLOCK, 0, stream>>>(grad, de_ws, r2_ws, part, nblk);
    tnep_reduce<<<1, BLOCK, 0, stream>>>(part, (float*)d_out, nblk);
}